// Round 1
// baseline (797.037 us; speedup 1.0000x reference)
//
#include <hip/hip_runtime.h>

#define DIMD 128
#define EPSV 1e-5f

// ---------------- edge-index dtype probe (int64 stored vs int32) ----------
__global__ void k_detect(const int* __restrict__ ei, int nchk, int* __restrict__ mode) {
    __shared__ int any;
    if (threadIdx.x == 0) any = 0;
    __syncthreads();
    for (int i = threadIdx.x; i < nchk; i += 256)
        if (ei[2 * i + 1] != 0) any = 1;   // benign race
    __syncthreads();
    if (threadIdx.x == 0) *mode = any ? 0 : 1;  // 1 => data is int64 pairs
}

__device__ __forceinline__ int load_src(const int* ei, int e, int E, int m) {
    return m ? ei[2 * e] : ei[e];
}
__device__ __forceinline__ int load_dst(const int* ei, int e, int E, int m) {
    return m ? ei[2 * (E + e)] : ei[E + e];
}

// ---------------- degree + in-count ---------------------------------------
__global__ void k_deg_count(const int* __restrict__ ei, const float* __restrict__ ew,
                            float* __restrict__ deg, int* __restrict__ cnt,
                            const int* __restrict__ modep, int E) {
    int e = blockIdx.x * 256 + threadIdx.x;
    if (e < E) {
        int m = *modep;
        int d = load_dst(ei, e, E, m);
        atomicAdd(&deg[d], ew[e]);
        atomicAdd(&cnt[d], 1);
    }
}

__global__ void k_deg_fin(const float* __restrict__ deg, float* __restrict__ dinv,
                          float* __restrict__ selfc, int N) {
    int i = blockIdx.x * 256 + threadIdx.x;
    if (i < N) {
        float d = deg[i] + 1.0f;
        dinv[i] = rsqrtf(d);
        selfc[i] = 1.0f / d;
    }
}

// ---------------- 3-kernel exclusive scan of cnt -> offs -------------------
__global__ void k_scanA(const int* __restrict__ cnt, int* __restrict__ offs,
                        int* __restrict__ bsum, int N) {
    __shared__ int sh[256];
    int tid = threadIdx.x;
    int i = blockIdx.x * 256 + tid;
    int v = (i < N) ? cnt[i] : 0;
    sh[tid] = v;
    __syncthreads();
    for (int off = 1; off < 256; off <<= 1) {
        int t = (tid >= off) ? sh[tid - off] : 0;
        __syncthreads();
        sh[tid] += t;
        __syncthreads();
    }
    if (i < N) offs[i] = sh[tid] - v;  // exclusive
    if (tid == 255) bsum[blockIdx.x] = sh[255];
}

__global__ void k_scanB(int* __restrict__ bsum, int* __restrict__ bbase, int NB) {
    __shared__ int sh[256];
    int tid = threadIdx.x;
    int v = (tid < NB) ? bsum[tid] : 0;
    sh[tid] = v;
    __syncthreads();
    for (int off = 1; off < 256; off <<= 1) {
        int t = (tid >= off) ? sh[tid - off] : 0;
        __syncthreads();
        sh[tid] += t;
        __syncthreads();
    }
    if (tid < NB) bbase[tid] = sh[tid] - v;
}

__global__ void k_scanC(const int* __restrict__ cnt, int* __restrict__ offs,
                        const int* __restrict__ bbase, int N) {
    int i = blockIdx.x * 256 + threadIdx.x;
    if (i < N) {
        int v = offs[i] + bbase[blockIdx.x];
        offs[i] = v;
        if (i == N - 1) offs[N] = v + cnt[i];
    }
}

// ---------------- CSR fill -------------------------------------------------
__global__ void k_fill(const int* __restrict__ ei, const float* __restrict__ ew,
                       const float* __restrict__ dinv, const int* __restrict__ offs,
                       int* __restrict__ cursor, int* __restrict__ csr_src,
                       float* __restrict__ csr_w, const int* __restrict__ modep, int E) {
    int e = blockIdx.x * 256 + threadIdx.x;
    if (e < E) {
        int m = *modep;
        int s = load_src(ei, e, E, m);
        int d = load_dst(ei, e, E, m);
        int pos = offs[d] + atomicAdd(&cursor[d], 1);
        csr_src[pos] = s;
        csr_w[pos] = dinv[d] * ew[e] * dinv[s];
    }
}

// ---------------- GEMM: Y[N,128] = X[N,128] @ W[128,128] (+ cb) ------------
__global__ __launch_bounds__(256) void k_gemm(const float* __restrict__ X,
                                              const float* __restrict__ W,
                                              const float* __restrict__ cb,
                                              float* __restrict__ Y, int N) {
    __shared__ float Wl[64 * 128];
    __shared__ float xl[8 * 64];
    int tid = threadIdx.x;
    int nl = tid >> 5, jg = tid & 31;
    int base = blockIdx.x * 8;
    float4 acc = {0.f, 0.f, 0.f, 0.f};
    for (int chunk = 0; chunk < 2; ++chunk) {
        int kc = chunk * 64;
        const float4* Wg = (const float4*)(W + (size_t)kc * 128);
#pragma unroll
        for (int r = 0; r < 8; r++) ((float4*)Wl)[r * 256 + tid] = Wg[r * 256 + tid];
        {
            int rr = tid >> 5;
            int kk = (tid & 31) * 2;
            int row = base + rr;
            float2 v = {0.f, 0.f};
            if (row < N) v = *(const float2*)(X + (size_t)row * 128 + kc + kk);
            xl[rr * 64 + kk] = v.x;
            xl[rr * 64 + kk + 1] = v.y;
        }
        __syncthreads();
#pragma unroll 8
        for (int k = 0; k < 64; k++) {
            float xv = xl[nl * 64 + k];
            float4 w4 = ((const float4*)Wl)[k * 32 + jg];
            acc.x += xv * w4.x;
            acc.y += xv * w4.y;
            acc.z += xv * w4.z;
            acc.w += xv * w4.w;
        }
        __syncthreads();
    }
    if (cb) {
        float4 c4 = ((const float4*)cb)[jg];
        acc.x += c4.x; acc.y += c4.y; acc.z += c4.z; acc.w += c4.w;
    }
    int n = base + nl;
    if (n < N) ((float4*)(Y + (size_t)n * 128))[jg] = acc;
}

// ---------------- aggregation + bias + relu + skip + BN-stats --------------
__global__ __launch_bounds__(256) void k_aggr(
    const float* __restrict__ xw, const float* __restrict__ latent,
    const int* __restrict__ csr_src, const float* __restrict__ csr_w,
    const int* __restrict__ offs, const float* __restrict__ selfc,
    const float* __restrict__ bias, float* __restrict__ T,
    float* __restrict__ gsum, float* __restrict__ gsq,
    int N, int relu, int nwaves) {
    __shared__ float ssum[128], ssq[128];
    int tid = threadIdx.x;
    if (tid < 128) { ssum[tid] = 0.f; ssq[tid] = 0.f; }
    __syncthreads();
    int lane = tid & 63;
    int wid = blockIdx.x * 4 + (tid >> 6);
    const float2* xw2 = (const float2*)xw;
    float2 b2 = ((const float2*)bias)[lane];
    float2 ts = {0.f, 0.f}, tq = {0.f, 0.f};
    for (int n = wid; n < N; n += nwaves) {
        int kb = offs[n], ke = offs[n + 1];
        float2 acc = {0.f, 0.f};
        for (int b0 = kb; b0 < ke; b0 += 64) {
            int e = b0 + lane;
            int s = 0;
            float w = 0.f;
            if (e < ke) { s = csr_src[e]; w = csr_w[e]; }
            int cnt = min(64, ke - b0);
            for (int t = 0; t < cnt; t++) {
                int ss = __shfl(s, t);
                float ww = __shfl(w, t);
                float2 v = xw2[(size_t)ss * 64 + lane];
                acc.x += ww * v.x;
                acc.y += ww * v.y;
            }
        }
        float sc = selfc[n];
        float2 xv = xw2[(size_t)n * 64 + lane];
        acc.x += sc * xv.x + b2.x;
        acc.y += sc * xv.y + b2.y;
        if (relu) { acc.x = fmaxf(acc.x, 0.f); acc.y = fmaxf(acc.y, 0.f); }
        float2 lv = ((const float2*)latent)[(size_t)n * 64 + lane];
        acc.x += lv.x;
        acc.y += lv.y;
        ((float2*)T)[(size_t)n * 64 + lane] = acc;
        ts.x += acc.x; ts.y += acc.y;
        tq.x += acc.x * acc.x; tq.y += acc.y * acc.y;
    }
    atomicAdd(&ssum[lane * 2], ts.x);
    atomicAdd(&ssum[lane * 2 + 1], ts.y);
    atomicAdd(&ssq[lane * 2], tq.x);
    atomicAdd(&ssq[lane * 2 + 1], tq.y);
    __syncthreads();
    if (tid < 128) {
        int copy = blockIdx.x & 31;
        atomicAdd(&gsum[copy * 128 + tid], ssum[tid]);
        atomicAdd(&gsq[copy * 128 + tid], ssq[tid]);
    }
}

// ---------------- BN stats finalize ---------------------------------------
__global__ void k_stats(const float* __restrict__ gsum, const float* __restrict__ gsq,
                        const float* __restrict__ gamma, const float* __restrict__ beta,
                        float* __restrict__ A, float* __restrict__ C, int N) {
    int j = threadIdx.x;  // 128
    float s = 0.f, q = 0.f;
    for (int c = 0; c < 32; c++) { s += gsum[c * 128 + j]; q += gsq[c * 128 + j]; }
    float mean = s / (float)N;
    float var = q / (float)N - mean * mean;
    float a = gamma[j] * rsqrtf(var + EPSV);
    A[j] = a;
    C[j] = beta[j] - a * mean;
}

// ---------------- fold BN affine into next layer's weights ----------------
__global__ void k_fusew(const float* __restrict__ W, const float* __restrict__ A,
                        float* __restrict__ Wf) {
    int idx = blockIdx.x * 256 + threadIdx.x;  // 16384
    int k = idx >> 7;
    Wf[idx] = A[k] * W[idx];
}

__global__ void k_fuseb(const float* __restrict__ W, const float* __restrict__ C,
                        float* __restrict__ cW) {
    int j = threadIdx.x;  // 128
    float acc = 0.f;
    for (int k = 0; k < 128; k++) acc += C[k] * W[k * 128 + j];
    cW[j] = acc;
}

// ---------------- final normalize of layer-2 output ------------------------
__global__ void k_bnorm(const float* __restrict__ T, const float* __restrict__ A,
                        const float* __restrict__ C, float* __restrict__ out, int total4) {
    int i = blockIdx.x * 256 + threadIdx.x;
    if (i < total4) {
        int jg = i & 31;
        float4 t = ((const float4*)T)[i];
        float4 a = ((const float4*)A)[jg];
        float4 c = ((const float4*)C)[jg];
        float4 r;
        r.x = a.x * t.x + c.x;
        r.y = a.y * t.y + c.y;
        r.z = a.z * t.z + c.z;
        r.w = a.w * t.w + c.w;
        ((float4*)out)[i] = r;
    }
}

extern "C" void kernel_launch(void* const* d_in, const int* in_sizes, int n_in,
                              void* d_out, int out_size, void* d_ws, size_t ws_size,
                              hipStream_t stream) {
    const float* latent = (const float*)d_in[0];
    const int* ei = (const int*)d_in[1];
    const float* ew = (const float*)d_in[2];
    const float* Ws = (const float*)d_in[3];
    const float* bs = (const float*)d_in[4];
    const float* gammas = (const float*)d_in[5];
    const float* betas = (const float*)d_in[6];
    float* out = (float*)d_out;

    const int N = in_sizes[0] / DIMD;
    const int E = in_sizes[1] / 2;
    const int NB = (N + 255) / 256;
    const size_t Np = (size_t)NB * 256;

    char* p = (char*)d_ws;
    auto alloc = [&](size_t b) -> char* {
        char* r = p;
        p += (b + 255) & ~(size_t)255;
        return r;
    };
    // ---- zero-initialized region (must stay first & contiguous) ----
    float* deg = (float*)alloc(Np * 4);
    int* cnt = (int*)alloc(Np * 4);
    int* cursor = (int*)alloc(Np * 4);
    float* gstats = (float*)alloc((size_t)3 * 2 * 32 * 128 * 4);  // [layer][sum/sq][copy][j]
    size_t zbytes = (size_t)(p - (char*)d_ws);
    // ---- rest ----
    int* mode = (int*)alloc(256);
    float* dinv = (float*)alloc((size_t)N * 4);
    float* selfc = (float*)alloc((size_t)N * 4);
    int* offs = (int*)alloc((size_t)(N + 1) * 4);
    int* bsum = (int*)alloc(256 * 4);
    int* bbase = (int*)alloc(256 * 4);
    float* A = (float*)alloc(128 * 4);
    float* C = (float*)alloc(128 * 4);
    float* cW = (float*)alloc(128 * 4);
    float* Wf = (float*)alloc((size_t)128 * 128 * 4);
    int* csr_src = (int*)alloc((size_t)E * 4);
    float* csr_w = (float*)alloc((size_t)E * 4);
    float* bufA = (float*)alloc((size_t)N * DIMD * 4);  // xw
    float* bufB = (float*)alloc((size_t)N * DIMD * 4);  // t

    hipMemsetAsync(d_ws, 0, zbytes, stream);

    int nchk = E < 4096 ? E : 4096;
    k_detect<<<1, 256, 0, stream>>>(ei, nchk, mode);
    k_deg_count<<<(E + 255) / 256, 256, 0, stream>>>(ei, ew, deg, cnt, mode, E);
    k_deg_fin<<<NB, 256, 0, stream>>>(deg, dinv, selfc, N);
    k_scanA<<<NB, 256, 0, stream>>>(cnt, offs, bsum, N);
    k_scanB<<<1, 256, 0, stream>>>(bsum, bbase, NB);
    k_scanC<<<NB, 256, 0, stream>>>(cnt, offs, bbase, N);
    k_fill<<<(E + 255) / 256, 256, 0, stream>>>(ei, ew, dinv, offs, cursor, csr_src, csr_w, mode, E);

    const float* gin = latent;
    for (int i = 0; i < 3; i++) {
        const float* Wp = (i == 0) ? Ws : Wf;
        const float* cbp = (i == 0) ? nullptr : cW;
        k_gemm<<<(N + 7) / 8, 256, 0, stream>>>(gin, Wp, cbp, bufA, N);
        float* gsum_i = gstats + (size_t)i * 2 * 32 * 128;
        float* gsq_i = gsum_i + 32 * 128;
        k_aggr<<<2048, 256, 0, stream>>>(bufA, latent, csr_src, csr_w, offs, selfc,
                                         bs + i * DIMD, bufB, gsum_i, gsq_i, N,
                                         (i != 1) ? 1 : 0, 8192);
        k_stats<<<1, 128, 0, stream>>>(gsum_i, gsq_i, gammas + i * DIMD, betas + i * DIMD, A, C, N);
        if (i < 2) {
            k_fusew<<<64, 256, 0, stream>>>(Ws + (size_t)(i + 1) * DIMD * DIMD, A, Wf);
            k_fuseb<<<1, 128, 0, stream>>>(Ws + (size_t)(i + 1) * DIMD * DIMD, C, cW);
            gin = bufB;  // next GEMM consumes un-normalized t (BN folded into Wf/cW)
        }
    }
    int total4 = N * DIMD / 4;
    k_bnorm<<<(total4 + 255) / 256, 256, 0, stream>>>(bufB, A, C, out, total4);
}

// Round 2
// 589.558 us; speedup vs baseline: 1.3519x; 1.3519x over previous
//
#include <hip/hip_runtime.h>

#define DIMD 128
#define EPSV 1e-5f

typedef _Float16 f16;
typedef f16 f16x2 __attribute__((ext_vector_type(2)));
typedef f16 f16x4 __attribute__((ext_vector_type(4)));

// ---------------- edge-index dtype probe (int64 stored vs int32) ----------
__global__ void k_detect(const int* __restrict__ ei, int nchk, int* __restrict__ mode) {
    __shared__ int any;
    if (threadIdx.x == 0) any = 0;
    __syncthreads();
    for (int i = threadIdx.x; i < nchk; i += 256)
        if (ei[2 * i + 1] != 0) any = 1;   // benign race
    __syncthreads();
    if (threadIdx.x == 0) *mode = any ? 0 : 1;  // 1 => data is int64 pairs
}

__device__ __forceinline__ int load_src(const int* ei, int e, int E, int m) {
    return m ? ei[2 * e] : ei[e];
}
__device__ __forceinline__ int load_dst(const int* ei, int e, int E, int m) {
    return m ? ei[2 * (E + e)] : ei[E + e];
}

// ---------------- rank + histogram (single atomic pass) --------------------
__global__ void k_rank(const int* __restrict__ ei, int* __restrict__ rank,
                       int* __restrict__ cnt, const int* __restrict__ modep, int E) {
    int e = blockIdx.x * 256 + threadIdx.x;
    if (e < E) {
        int m = *modep;
        int d = load_dst(ei, e, E, m);
        rank[e] = atomicAdd(&cnt[d], 1);
    }
}

// ---------------- 3-kernel exclusive scan of cnt -> offs -------------------
__global__ void k_scanA(const int* __restrict__ cnt, int* __restrict__ offs,
                        int* __restrict__ bsum, int N) {
    __shared__ int sh[256];
    int tid = threadIdx.x;
    int i = blockIdx.x * 256 + tid;
    int v = (i < N) ? cnt[i] : 0;
    sh[tid] = v;
    __syncthreads();
    for (int off = 1; off < 256; off <<= 1) {
        int t = (tid >= off) ? sh[tid - off] : 0;
        __syncthreads();
        sh[tid] += t;
        __syncthreads();
    }
    if (i < N) offs[i] = sh[tid] - v;  // exclusive
    if (tid == 255) bsum[blockIdx.x] = sh[255];
}

__global__ void k_scanB(int* __restrict__ bsum, int* __restrict__ bbase, int NB) {
    __shared__ int sh[256];
    int tid = threadIdx.x;
    int v = (tid < NB) ? bsum[tid] : 0;
    sh[tid] = v;
    __syncthreads();
    for (int off = 1; off < 256; off <<= 1) {
        int t = (tid >= off) ? sh[tid - off] : 0;
        __syncthreads();
        sh[tid] += t;
        __syncthreads();
    }
    if (tid < NB) bbase[tid] = sh[tid] - v;
}

__global__ void k_scanC(const int* __restrict__ cnt, int* __restrict__ offs,
                        const int* __restrict__ bbase, int N) {
    int i = blockIdx.x * 256 + threadIdx.x;
    if (i < N) {
        int v = offs[i] + bbase[blockIdx.x];
        offs[i] = v;
        if (i == N - 1) offs[N] = v + cnt[i];
    }
}

// ---------------- CSR fill (atomic-free): csr = {src, raw ew} -------------
__global__ void k_fill(const int* __restrict__ ei, const float* __restrict__ ew,
                       const int* __restrict__ offs, const int* __restrict__ rank,
                       int2* __restrict__ csr, const int* __restrict__ modep, int E) {
    int e = blockIdx.x * 256 + threadIdx.x;
    if (e < E) {
        int m = *modep;
        int s = load_src(ei, e, E, m);
        int d = load_dst(ei, e, E, m);
        int pos = offs[d] + rank[e];
        csr[pos] = make_int2(s, __float_as_int(ew[e]));
    }
}

// ---------------- degree from CSR (coalesced) -> dinv ----------------------
__global__ __launch_bounds__(256) void k_deg(const int2* __restrict__ csr,
                                             const int* __restrict__ offs,
                                             float* __restrict__ dinv, int N, int nwaves) {
    int lane = threadIdx.x & 63;
    int wid = blockIdx.x * 4 + (threadIdx.x >> 6);
    for (int n = wid; n < N; n += nwaves) {
        int kb = offs[n], ke = offs[n + 1];
        float s = 0.f;
        for (int e = kb + lane; e < ke; e += 64) s += __int_as_float(csr[e].y);
        for (int off = 32; off; off >>= 1) s += __shfl_down(s, off);
        if (lane == 0) dinv[n] = rsqrtf(s + 1.0f);
    }
}

// ------- GEMM: y[N,128] = fp16( dinv[row] * (X[N,128] @ W + cb) ) ---------
__global__ __launch_bounds__(256) void k_gemm(const float* __restrict__ X,
                                              const float* __restrict__ W,
                                              const float* __restrict__ cb,
                                              const float* __restrict__ dinv,
                                              f16x4* __restrict__ Y, int N) {
    __shared__ float Wl[64 * 128];
    __shared__ float xl[8 * 64];
    int tid = threadIdx.x;
    int nl = tid >> 5, jg = tid & 31;
    int base = blockIdx.x * 8;
    float4 acc = {0.f, 0.f, 0.f, 0.f};
    for (int chunk = 0; chunk < 2; ++chunk) {
        int kc = chunk * 64;
        const float4* Wg = (const float4*)(W + (size_t)kc * 128);
#pragma unroll
        for (int r = 0; r < 8; r++) ((float4*)Wl)[r * 256 + tid] = Wg[r * 256 + tid];
        {
            int rr = tid >> 5;
            int kk = (tid & 31) * 2;
            int row = base + rr;
            float2 v = {0.f, 0.f};
            if (row < N) v = *(const float2*)(X + (size_t)row * 128 + kc + kk);
            xl[rr * 64 + kk] = v.x;
            xl[rr * 64 + kk + 1] = v.y;
        }
        __syncthreads();
#pragma unroll 8
        for (int k = 0; k < 64; k++) {
            float xv = xl[nl * 64 + k];
            float4 w4 = ((const float4*)Wl)[k * 32 + jg];
            acc.x += xv * w4.x;
            acc.y += xv * w4.y;
            acc.z += xv * w4.z;
            acc.w += xv * w4.w;
        }
        __syncthreads();
    }
    if (cb) {
        float4 c4 = ((const float4*)cb)[jg];
        acc.x += c4.x; acc.y += c4.y; acc.z += c4.z; acc.w += c4.w;
    }
    int n = base + nl;
    if (n < N) {
        float dv = dinv[n];
        f16x4 o;
        o.x = (f16)(acc.x * dv);
        o.y = (f16)(acc.y * dv);
        o.z = (f16)(acc.z * dv);
        o.w = (f16)(acc.w * dv);
        Y[(size_t)n * 32 + jg] = o;
    }
}

// ------- aggregation: t = dinv*(sum ew*y[src] + y[n]) + b (+relu) + latent -
__global__ __launch_bounds__(256) void k_aggr(
    const f16x2* __restrict__ y, const float* __restrict__ latent,
    const int2* __restrict__ csr, const int* __restrict__ offs,
    const float* __restrict__ dinv, const float* __restrict__ bias,
    float* __restrict__ T, float* __restrict__ gsum, float* __restrict__ gsq,
    int N, int relu, int nwaves) {
    __shared__ float ssum[128], ssq[128];
    int tid = threadIdx.x;
    if (tid < 128) { ssum[tid] = 0.f; ssq[tid] = 0.f; }
    __syncthreads();
    int lane = tid & 63;
    int wid = blockIdx.x * 4 + (tid >> 6);
    float2 b2 = ((const float2*)bias)[lane];
    float2 ts = {0.f, 0.f}, tq = {0.f, 0.f};
    for (int n = wid; n < N; n += nwaves) {
        int kb = offs[n], ke = offs[n + 1];
        float2 acc = {0.f, 0.f};
        for (int b0 = kb; b0 < ke; b0 += 64) {
            int e = b0 + lane;
            int2 v = make_int2(0, 0);
            if (e < ke) v = csr[e];
            int cnt = min(64, ke - b0);
            for (int t = 0; t < cnt; t++) {
                int ss = __shfl(v.x, t);
                float ww = __shfl(__int_as_float(v.y), t);
                f16x2 p = y[(size_t)ss * 64 + lane];
                acc.x += ww * (float)p.x;
                acc.y += ww * (float)p.y;
            }
        }
        f16x2 sv = y[(size_t)n * 64 + lane];
        float dv = dinv[n];
        acc.x = (acc.x + (float)sv.x) * dv + b2.x;
        acc.y = (acc.y + (float)sv.y) * dv + b2.y;
        if (relu) { acc.x = fmaxf(acc.x, 0.f); acc.y = fmaxf(acc.y, 0.f); }
        float2 lv = ((const float2*)latent)[(size_t)n * 64 + lane];
        acc.x += lv.x;
        acc.y += lv.y;
        ((float2*)T)[(size_t)n * 64 + lane] = acc;
        ts.x += acc.x; ts.y += acc.y;
        tq.x += acc.x * acc.x; tq.y += acc.y * acc.y;
    }
    atomicAdd(&ssum[lane * 2], ts.x);
    atomicAdd(&ssum[lane * 2 + 1], ts.y);
    atomicAdd(&ssq[lane * 2], tq.x);
    atomicAdd(&ssq[lane * 2 + 1], tq.y);
    __syncthreads();
    if (tid < 128) {
        int copy = blockIdx.x & 31;
        atomicAdd(&gsum[copy * 128 + tid], ssum[tid]);
        atomicAdd(&gsq[copy * 128 + tid], ssq[tid]);
    }
}

// ---------------- BN stats finalize ---------------------------------------
__global__ void k_stats(const float* __restrict__ gsum, const float* __restrict__ gsq,
                        const float* __restrict__ gamma, const float* __restrict__ beta,
                        float* __restrict__ A, float* __restrict__ C, int N) {
    int j = threadIdx.x;  // 128
    float s = 0.f, q = 0.f;
    for (int c = 0; c < 32; c++) { s += gsum[c * 128 + j]; q += gsq[c * 128 + j]; }
    float mean = s / (float)N;
    float var = q / (float)N - mean * mean;
    float a = gamma[j] * rsqrtf(var + EPSV);
    A[j] = a;
    C[j] = beta[j] - a * mean;
}

// ---------------- fold BN affine into next layer's weights ----------------
__global__ void k_fusew(const float* __restrict__ W, const float* __restrict__ A,
                        float* __restrict__ Wf) {
    int idx = blockIdx.x * 256 + threadIdx.x;  // 16384
    int k = idx >> 7;
    Wf[idx] = A[k] * W[idx];
}

__global__ void k_fuseb(const float* __restrict__ W, const float* __restrict__ C,
                        float* __restrict__ cW) {
    int j = threadIdx.x;  // 128
    float acc = 0.f;
    for (int k = 0; k < 128; k++) acc += C[k] * W[k * 128 + j];
    cW[j] = acc;
}

// ---------------- final normalize of layer-2 output ------------------------
__global__ void k_bnorm(const float* __restrict__ T, const float* __restrict__ A,
                        const float* __restrict__ C, float* __restrict__ out, int total4) {
    int i = blockIdx.x * 256 + threadIdx.x;
    if (i < total4) {
        int jg = i & 31;
        float4 t = ((const float4*)T)[i];
        float4 a = ((const float4*)A)[jg];
        float4 c = ((const float4*)C)[jg];
        float4 r;
        r.x = a.x * t.x + c.x;
        r.y = a.y * t.y + c.y;
        r.z = a.z * t.z + c.z;
        r.w = a.w * t.w + c.w;
        ((float4*)out)[i] = r;
    }
}

extern "C" void kernel_launch(void* const* d_in, const int* in_sizes, int n_in,
                              void* d_out, int out_size, void* d_ws, size_t ws_size,
                              hipStream_t stream) {
    const float* latent = (const float*)d_in[0];
    const int* ei = (const int*)d_in[1];
    const float* ew = (const float*)d_in[2];
    const float* Ws = (const float*)d_in[3];
    const float* bs = (const float*)d_in[4];
    const float* gammas = (const float*)d_in[5];
    const float* betas = (const float*)d_in[6];
    float* out = (float*)d_out;

    const int N = in_sizes[0] / DIMD;
    const int E = in_sizes[1] / 2;
    const int NB = (N + 255) / 256;
    const size_t Np = (size_t)NB * 256;

    char* p = (char*)d_ws;
    auto alloc = [&](size_t b) -> char* {
        char* r = p;
        p += (b + 255) & ~(size_t)255;
        return r;
    };
    // ---- zero-initialized region (must stay first & contiguous) ----
    int* cnt = (int*)alloc(Np * 4);
    float* gstats = (float*)alloc((size_t)3 * 2 * 32 * 128 * 4);  // [layer][sum/sq][copy][j]
    size_t zbytes = (size_t)(p - (char*)d_ws);
    // ---- rest ----
    int* mode = (int*)alloc(256);
    float* dinv = (float*)alloc((size_t)N * 4);
    int* offs = (int*)alloc((size_t)(N + 1) * 4);
    int* bsum = (int*)alloc(256 * 4);
    int* bbase = (int*)alloc(256 * 4);
    float* A = (float*)alloc(128 * 4);
    float* C = (float*)alloc(128 * 4);
    float* cW = (float*)alloc(128 * 4);
    float* Wf = (float*)alloc((size_t)128 * 128 * 4);
    int* rank = (int*)alloc((size_t)E * 4);
    int2* csr = (int2*)alloc((size_t)E * 8);
    f16x4* bufY = (f16x4*)alloc((size_t)N * DIMD * 2);   // y (fp16)
    float* bufB = (float*)alloc((size_t)N * DIMD * 4);   // t (fp32)

    hipMemsetAsync(d_ws, 0, zbytes, stream);

    int nchk = E < 4096 ? E : 4096;
    k_detect<<<1, 256, 0, stream>>>(ei, nchk, mode);
    k_rank<<<(E + 255) / 256, 256, 0, stream>>>(ei, rank, cnt, mode, E);
    k_scanA<<<NB, 256, 0, stream>>>(cnt, offs, bsum, N);
    k_scanB<<<1, 256, 0, stream>>>(bsum, bbase, NB);
    k_scanC<<<NB, 256, 0, stream>>>(cnt, offs, bbase, N);
    k_fill<<<(E + 255) / 256, 256, 0, stream>>>(ei, ew, offs, rank, csr, mode, E);
    k_deg<<<512, 256, 0, stream>>>(csr, offs, dinv, N, 2048);

    const float* gin = latent;
    for (int i = 0; i < 3; i++) {
        const float* Wp = (i == 0) ? Ws : Wf;
        const float* cbp = (i == 0) ? nullptr : cW;
        k_gemm<<<(N + 7) / 8, 256, 0, stream>>>(gin, Wp, cbp, dinv, bufY, N);
        float* gsum_i = gstats + (size_t)i * 2 * 32 * 128;
        float* gsq_i = gsum_i + 32 * 128;
        k_aggr<<<2048, 256, 0, stream>>>((const f16x2*)bufY, latent, csr, offs, dinv,
                                         bs + i * DIMD, bufB, gsum_i, gsq_i, N,
                                         (i != 1) ? 1 : 0, 8192);
        k_stats<<<1, 128, 0, stream>>>(gsum_i, gsq_i, gammas + i * DIMD, betas + i * DIMD, A, C, N);
        if (i < 2) {
            k_fusew<<<64, 256, 0, stream>>>(Ws + (size_t)(i + 1) * DIMD * DIMD, A, Wf);
            k_fuseb<<<1, 128, 0, stream>>>(Ws + (size_t)(i + 1) * DIMD * DIMD, C, cW);
            gin = bufB;  // next GEMM consumes un-normalized t (BN folded into Wf/cW)
        }
    }
    int total4 = N * DIMD / 4;
    k_bnorm<<<(total4 + 255) / 256, 256, 0, stream>>>(bufB, A, C, out, total4);
}

// Round 3
// 460.867 us; speedup vs baseline: 1.7294x; 1.2792x over previous
//
#include <hip/hip_runtime.h>

#define DIMD 128
#define EPSV 1e-5f

typedef _Float16 f16;
typedef f16 f16x2 __attribute__((ext_vector_type(2)));
typedef f16 f16x4 __attribute__((ext_vector_type(4)));

// ---------------- edge-index dtype probe (int64 stored vs int32) ----------
__global__ void k_detect(const int* __restrict__ ei, int nchk, int* __restrict__ mode) {
    __shared__ int any;
    if (threadIdx.x == 0) any = 0;
    __syncthreads();
    for (int i = threadIdx.x; i < nchk; i += 256)
        if (ei[2 * i + 1] != 0) any = 1;   // benign race
    __syncthreads();
    if (threadIdx.x == 0) *mode = any ? 0 : 1;  // 1 => data is int64 pairs
}

__device__ __forceinline__ int load_src(const int* ei, int e, int E, int m) {
    return m ? ei[2 * e] : ei[e];
}
__device__ __forceinline__ int load_dst(const int* ei, int e, int E, int m) {
    return m ? ei[2 * (E + e)] : ei[E + e];
}

// ---------------- rank + histogram (single atomic pass) --------------------
__global__ void k_rank(const int* __restrict__ ei, int* __restrict__ rank,
                       int* __restrict__ cnt, const int* __restrict__ modep, int E) {
    int e = blockIdx.x * 256 + threadIdx.x;
    if (e < E) {
        int m = *modep;
        int d = load_dst(ei, e, E, m);
        rank[e] = atomicAdd(&cnt[d], 1);
    }
}

// ---------------- 3-kernel exclusive scan of cnt -> offs -------------------
__global__ void k_scanA(const int* __restrict__ cnt, int* __restrict__ offs,
                        int* __restrict__ bsum, int N) {
    __shared__ int sh[256];
    int tid = threadIdx.x;
    int i = blockIdx.x * 256 + tid;
    int v = (i < N) ? cnt[i] : 0;
    sh[tid] = v;
    __syncthreads();
    for (int off = 1; off < 256; off <<= 1) {
        int t = (tid >= off) ? sh[tid - off] : 0;
        __syncthreads();
        sh[tid] += t;
        __syncthreads();
    }
    if (i < N) offs[i] = sh[tid] - v;  // exclusive
    if (tid == 255) bsum[blockIdx.x] = sh[255];
}

__global__ void k_scanB(int* __restrict__ bsum, int* __restrict__ bbase, int NB) {
    __shared__ int sh[256];
    int tid = threadIdx.x;
    int v = (tid < NB) ? bsum[tid] : 0;
    sh[tid] = v;
    __syncthreads();
    for (int off = 1; off < 256; off <<= 1) {
        int t = (tid >= off) ? sh[tid - off] : 0;
        __syncthreads();
        sh[tid] += t;
        __syncthreads();
    }
    if (tid < NB) bbase[tid] = sh[tid] - v;
}

__global__ void k_scanC(const int* __restrict__ cnt, int* __restrict__ offs,
                        const int* __restrict__ bbase, int N) {
    int i = blockIdx.x * 256 + threadIdx.x;
    if (i < N) {
        int v = offs[i] + bbase[blockIdx.x];
        offs[i] = v;
        if (i == N - 1) offs[N] = v + cnt[i];
    }
}

// ---------------- CSR fill (atomic-free): csr = {src, raw ew} -------------
__global__ void k_fill(const int* __restrict__ ei, const float* __restrict__ ew,
                       const int* __restrict__ offs, const int* __restrict__ rank,
                       int2* __restrict__ csr, const int* __restrict__ modep, int E) {
    int e = blockIdx.x * 256 + threadIdx.x;
    if (e < E) {
        int m = *modep;
        int s = load_src(ei, e, E, m);
        int d = load_dst(ei, e, E, m);
        int pos = offs[d] + rank[e];
        csr[pos] = make_int2(s, __float_as_int(ew[e]));
    }
}

// ---------------- degree from CSR (coalesced) -> dinv ----------------------
__global__ __launch_bounds__(256) void k_deg(const int2* __restrict__ csr,
                                             const int* __restrict__ offs,
                                             float* __restrict__ dinv, int N, int nwaves) {
    int lane = threadIdx.x & 63;
    int wid = blockIdx.x * 4 + (threadIdx.x >> 6);
    for (int n = wid; n < N; n += nwaves) {
        int kb = offs[n], ke = offs[n + 1];
        float s = 0.f;
        for (int e = kb + lane; e < ke; e += 64) s += __int_as_float(csr[e].y);
        for (int off = 32; off; off >>= 1) s += __shfl_down(s, off);
        if (lane == 0) dinv[n] = rsqrtf(s + 1.0f);
    }
}

// ------- GEMM: y[N,128] = fp16( dinv[row] * (X[N,128] @ W + cb) ) ---------
__global__ __launch_bounds__(256) void k_gemm(const float* __restrict__ X,
                                              const float* __restrict__ W,
                                              const float* __restrict__ cb,
                                              const float* __restrict__ dinv,
                                              f16x4* __restrict__ Y, int N) {
    __shared__ float Wl[64 * 128];
    __shared__ float xl[8 * 64];
    int tid = threadIdx.x;
    int nl = tid >> 5, jg = tid & 31;
    int base = blockIdx.x * 8;
    float4 acc = {0.f, 0.f, 0.f, 0.f};
    for (int chunk = 0; chunk < 2; ++chunk) {
        int kc = chunk * 64;
        const float4* Wg = (const float4*)(W + (size_t)kc * 128);
#pragma unroll
        for (int r = 0; r < 8; r++) ((float4*)Wl)[r * 256 + tid] = Wg[r * 256 + tid];
        {
            int rr = tid >> 5;
            int kk = (tid & 31) * 2;
            int row = base + rr;
            float2 v = {0.f, 0.f};
            if (row < N) v = *(const float2*)(X + (size_t)row * 128 + kc + kk);
            xl[rr * 64 + kk] = v.x;
            xl[rr * 64 + kk + 1] = v.y;
        }
        __syncthreads();
#pragma unroll 8
        for (int k = 0; k < 64; k++) {
            float xv = xl[nl * 64 + k];
            float4 w4 = ((const float4*)Wl)[k * 32 + jg];
            acc.x += xv * w4.x;
            acc.y += xv * w4.y;
            acc.z += xv * w4.z;
            acc.w += xv * w4.w;
        }
        __syncthreads();
    }
    if (cb) {
        float4 c4 = ((const float4*)cb)[jg];
        acc.x += c4.x; acc.y += c4.y; acc.z += c4.z; acc.w += c4.w;
    }
    int n = base + nl;
    if (n < N) {
        float dv = dinv[n];
        f16x4 o;
        o.x = (f16)(acc.x * dv);
        o.y = (f16)(acc.y * dv);
        o.z = (f16)(acc.z * dv);
        o.w = (f16)(acc.w * dv);
        Y[(size_t)n * 32 + jg] = o;
    }
}

// ------- aggregation: t = dinv*(sum ew*y[src] + y[n]) + b (+relu) + latent -
// readlane-broadcast + 8-deep unrolled gathers (padded with w=0 slots)
__global__ __launch_bounds__(256) void k_aggr(
    const f16x2* __restrict__ y, const float* __restrict__ latent,
    const int2* __restrict__ csr, const int* __restrict__ offs,
    const float* __restrict__ dinv, const float* __restrict__ bias,
    float* __restrict__ T, float* __restrict__ gsum, float* __restrict__ gsq,
    int N, int relu, int nwaves) {
    __shared__ float ssum[128], ssq[128];
    int tid = threadIdx.x;
    if (tid < 128) { ssum[tid] = 0.f; ssq[tid] = 0.f; }
    __syncthreads();
    int lane = tid & 63;
    int wid = blockIdx.x * 4 + (tid >> 6);
    float2 b2 = ((const float2*)bias)[lane];
    float2 ts = {0.f, 0.f}, tq = {0.f, 0.f};
    for (int n = wid; n < N; n += nwaves) {
        int kb = offs[n], ke = offs[n + 1];
        float2 acc = {0.f, 0.f};
        for (int b0 = kb; b0 < ke; b0 += 64) {
            int e = b0 + lane;
            int2 v = make_int2(0, 0);
            if (e < ke) v = csr[e];
            int cnt8 = (min(64, ke - b0) + 7) & ~7;  // wave-uniform
            for (int t0 = 0; t0 < cnt8; t0 += 8) {
#pragma unroll
                for (int u = 0; u < 8; u++) {
                    int t = t0 + u;
                    int ss = __builtin_amdgcn_readlane(v.x, t);
                    float ww = __uint_as_float(
                        (unsigned)__builtin_amdgcn_readlane(v.y, t));
                    f16x2 p = y[(size_t)ss * 64 + lane];
                    acc.x += ww * (float)p.x;
                    acc.y += ww * (float)p.y;
                }
            }
        }
        f16x2 sv = y[(size_t)n * 64 + lane];
        float dv = dinv[n];
        acc.x = (acc.x + (float)sv.x) * dv + b2.x;
        acc.y = (acc.y + (float)sv.y) * dv + b2.y;
        if (relu) { acc.x = fmaxf(acc.x, 0.f); acc.y = fmaxf(acc.y, 0.f); }
        float2 lv = ((const float2*)latent)[(size_t)n * 64 + lane];
        acc.x += lv.x;
        acc.y += lv.y;
        ((float2*)T)[(size_t)n * 64 + lane] = acc;
        ts.x += acc.x; ts.y += acc.y;
        tq.x += acc.x * acc.x; tq.y += acc.y * acc.y;
    }
    atomicAdd(&ssum[lane * 2], ts.x);
    atomicAdd(&ssum[lane * 2 + 1], ts.y);
    atomicAdd(&ssq[lane * 2], tq.x);
    atomicAdd(&ssq[lane * 2 + 1], tq.y);
    __syncthreads();
    if (tid < 128) {
        int copy = blockIdx.x & 31;
        atomicAdd(&gsum[copy * 128 + tid], ssum[tid]);
        atomicAdd(&gsq[copy * 128 + tid], ssq[tid]);
    }
}

// ---------------- BN stats finalize ---------------------------------------
__global__ void k_stats(const float* __restrict__ gsum, const float* __restrict__ gsq,
                        const float* __restrict__ gamma, const float* __restrict__ beta,
                        float* __restrict__ A, float* __restrict__ C, int N) {
    int j = threadIdx.x;  // 128
    float s = 0.f, q = 0.f;
    for (int c = 0; c < 32; c++) { s += gsum[c * 128 + j]; q += gsq[c * 128 + j]; }
    float mean = s / (float)N;
    float var = q / (float)N - mean * mean;
    float a = gamma[j] * rsqrtf(var + EPSV);
    A[j] = a;
    C[j] = beta[j] - a * mean;
}

// ---------------- fold BN affine into next layer's weights ----------------
__global__ void k_fusew(const float* __restrict__ W, const float* __restrict__ A,
                        float* __restrict__ Wf) {
    int idx = blockIdx.x * 256 + threadIdx.x;  // 16384
    int k = idx >> 7;
    Wf[idx] = A[k] * W[idx];
}

__global__ void k_fuseb(const float* __restrict__ W, const float* __restrict__ C,
                        float* __restrict__ cW) {
    int j = threadIdx.x;  // 128
    float acc = 0.f;
    for (int k = 0; k < 128; k++) acc += C[k] * W[k * 128 + j];
    cW[j] = acc;
}

// ---------------- final normalize of layer-2 output ------------------------
__global__ void k_bnorm(const float* __restrict__ T, const float* __restrict__ A,
                        const float* __restrict__ C, float* __restrict__ out, int total4) {
    int i = blockIdx.x * 256 + threadIdx.x;
    if (i < total4) {
        int jg = i & 31;
        float4 t = ((const float4*)T)[i];
        float4 a = ((const float4*)A)[jg];
        float4 c = ((const float4*)C)[jg];
        float4 r;
        r.x = a.x * t.x + c.x;
        r.y = a.y * t.y + c.y;
        r.z = a.z * t.z + c.z;
        r.w = a.w * t.w + c.w;
        ((float4*)out)[i] = r;
    }
}

extern "C" void kernel_launch(void* const* d_in, const int* in_sizes, int n_in,
                              void* d_out, int out_size, void* d_ws, size_t ws_size,
                              hipStream_t stream) {
    const float* latent = (const float*)d_in[0];
    const int* ei = (const int*)d_in[1];
    const float* ew = (const float*)d_in[2];
    const float* Ws = (const float*)d_in[3];
    const float* bs = (const float*)d_in[4];
    const float* gammas = (const float*)d_in[5];
    const float* betas = (const float*)d_in[6];
    float* out = (float*)d_out;

    const int N = in_sizes[0] / DIMD;
    const int E = in_sizes[1] / 2;
    const int NB = (N + 255) / 256;
    const size_t Np = (size_t)NB * 256;

    char* p = (char*)d_ws;
    auto alloc = [&](size_t b) -> char* {
        char* r = p;
        p += (b + 255) & ~(size_t)255;
        return r;
    };
    // ---- zero-initialized region (must stay first & contiguous) ----
    int* cnt = (int*)alloc(Np * 4);
    float* gstats = (float*)alloc((size_t)3 * 2 * 32 * 128 * 4);  // [layer][sum/sq][copy][j]
    size_t zbytes = (size_t)(p - (char*)d_ws);
    // ---- rest ----
    int* mode = (int*)alloc(256);
    float* dinv = (float*)alloc((size_t)N * 4);
    int* offs = (int*)alloc((size_t)(N + 1) * 4);
    int* bsum = (int*)alloc(256 * 4);
    int* bbase = (int*)alloc(256 * 4);
    float* A = (float*)alloc(128 * 4);
    float* C = (float*)alloc(128 * 4);
    float* cW = (float*)alloc(128 * 4);
    float* Wf = (float*)alloc((size_t)128 * 128 * 4);
    int* rank = (int*)alloc((size_t)E * 4);
    int2* csr = (int2*)alloc((size_t)E * 8);
    f16x4* bufY = (f16x4*)alloc((size_t)N * DIMD * 2);   // y (fp16)
    float* bufB = (float*)alloc((size_t)N * DIMD * 4);   // t (fp32)

    hipMemsetAsync(d_ws, 0, zbytes, stream);

    int nchk = E < 4096 ? E : 4096;
    k_detect<<<1, 256, 0, stream>>>(ei, nchk, mode);
    k_rank<<<(E + 255) / 256, 256, 0, stream>>>(ei, rank, cnt, mode, E);
    k_scanA<<<NB, 256, 0, stream>>>(cnt, offs, bsum, N);
    k_scanB<<<1, 256, 0, stream>>>(bsum, bbase, NB);
    k_scanC<<<NB, 256, 0, stream>>>(cnt, offs, bbase, N);
    k_fill<<<(E + 255) / 256, 256, 0, stream>>>(ei, ew, offs, rank, csr, mode, E);
    k_deg<<<512, 256, 0, stream>>>(csr, offs, dinv, N, 2048);

    const float* gin = latent;
    for (int i = 0; i < 3; i++) {
        const float* Wp = (i == 0) ? Ws : Wf;
        const float* cbp = (i == 0) ? nullptr : cW;
        k_gemm<<<(N + 7) / 8, 256, 0, stream>>>(gin, Wp, cbp, dinv, bufY, N);
        float* gsum_i = gstats + (size_t)i * 2 * 32 * 128;
        float* gsq_i = gsum_i + 32 * 128;
        k_aggr<<<2048, 256, 0, stream>>>((const f16x2*)bufY, latent, csr, offs, dinv,
                                         bs + i * DIMD, bufB, gsum_i, gsq_i, N,
                                         (i != 1) ? 1 : 0, 8192);
        k_stats<<<1, 128, 0, stream>>>(gsum_i, gsq_i, gammas + i * DIMD, betas + i * DIMD, A, C, N);
        if (i < 2) {
            k_fusew<<<64, 256, 0, stream>>>(Ws + (size_t)(i + 1) * DIMD * DIMD, A, Wf);
            k_fuseb<<<1, 128, 0, stream>>>(Ws + (size_t)(i + 1) * DIMD * DIMD, C, cW);
            gin = bufB;  // next GEMM consumes un-normalized t (BN folded into Wf/cW)
        }
    }
    int total4 = N * DIMD / 4;
    k_bnorm<<<(total4 + 255) / 256, 256, 0, stream>>>(bufB, A, C, out, total4);
}